// Round 5
// baseline (8176.814 us; speedup 1.0000x reference)
//
#include <hip/hip_runtime.h>
#include <math.h>

#define S_LEN 4096
#define HDIRC 256
#define NTAG 10
#define START_TAG 8
#define STOP_TAG 9
#define NEGV -10000.0f

// -------- workspace layout (float units) --------
#define XW_OFF 0UL
#define XW_SZ  (2UL * S_LEN * 1024)          // xw[dir][t][1024]
#define HS_OFF (XW_OFF + XW_SZ)
#define HS_SZ  (2UL * S_LEN * 256)           // hs[dir][t][256] (dir1 indexed by backward step)
#define WT_OFF (HS_OFF + HS_SZ)
#define WT_SZ  (2UL * 256 * 1024)            // WihT[dir][k][r]
#define FE_OFF (WT_OFF + WT_SZ)
#define FE_SZ  ((size_t)S_LEN * NTAG)        // feats[t][tag]
#define RING_OFF (FE_OFF + FE_SZ)            // even float offset -> 8B aligned
#define RING_SZ (2UL * 2 * 256 * 2)          // u64 ring[dir][slot][dim], as floats

// ---------------- Wih transpose: [1024][256] -> [256][1024] ----------------
__global__ void transpose_wih(const float* __restrict__ wf,
                              const float* __restrict__ wb,
                              float* __restrict__ wT) {
    __shared__ float tile[32][33];
    const float* src = blockIdx.z ? wb : wf;
    float* dst = wT + (size_t)blockIdx.z * 256 * 1024;
    int x = blockIdx.x * 32 + threadIdx.x;   // k  (0..255)
    int y = blockIdx.y * 32 + threadIdx.y;   // r  (0..1023)
    tile[threadIdx.y][threadIdx.x] = src[y * 256 + x];
    __syncthreads();
    int ko = blockIdx.x * 32 + threadIdx.y;
    int ro = blockIdx.y * 32 + threadIdx.x;
    dst[(size_t)ko * 1024 + ro] = tile[threadIdx.x][threadIdx.y];
}

// ---------------- xW = emb[sent] @ Wih^T + (bih+bhh) ----------------
__global__ __launch_bounds__(256) void xw_gemm(
    const int* __restrict__ sent, const float* __restrict__ emb,
    const float* __restrict__ wT,
    const float* __restrict__ bih_f, const float* __restrict__ bhh_f,
    const float* __restrict__ bih_b, const float* __restrict__ bhh_b,
    float* __restrict__ xw) {
    int dir = blockIdx.y;
    int t0 = blockIdx.x * 16;
    int tid = threadIdx.x;
    __shared__ __align__(16) float xs[16][256];
    for (int i = 0; i < 16; ++i) {
        int t = t0 + i;
        int pos = dir ? (S_LEN - 1 - t) : t;
        int idx = sent[pos];
        xs[i][tid] = emb[(size_t)idx * 256 + tid];
    }
    __syncthreads();
    const float* w = wT + (size_t)dir * 256 * 1024;
    const float* bi = dir ? bih_b : bih_f;
    const float* bh = dir ? bhh_b : bhh_f;
    float4 bv;
    bv.x = bi[4 * tid + 0] + bh[4 * tid + 0];
    bv.y = bi[4 * tid + 1] + bh[4 * tid + 1];
    bv.z = bi[4 * tid + 2] + bh[4 * tid + 2];
    bv.w = bi[4 * tid + 3] + bh[4 * tid + 3];
    float4 acc[16];
#pragma unroll
    for (int i = 0; i < 16; ++i) acc[i] = bv;
    for (int k4 = 0; k4 < 64; ++k4) {
        float4 w0 = ((const float4*)(w + (size_t)(4 * k4 + 0) * 1024))[tid];
        float4 w1 = ((const float4*)(w + (size_t)(4 * k4 + 1) * 1024))[tid];
        float4 w2 = ((const float4*)(w + (size_t)(4 * k4 + 2) * 1024))[tid];
        float4 w3 = ((const float4*)(w + (size_t)(4 * k4 + 3) * 1024))[tid];
#pragma unroll
        for (int i = 0; i < 16; ++i) {
            float4 xv = *(const float4*)&xs[i][4 * k4];
            acc[i].x = fmaf(w0.x, xv.x, acc[i].x);
            acc[i].y = fmaf(w0.y, xv.x, acc[i].y);
            acc[i].z = fmaf(w0.z, xv.x, acc[i].z);
            acc[i].w = fmaf(w0.w, xv.x, acc[i].w);
            acc[i].x = fmaf(w1.x, xv.y, acc[i].x);
            acc[i].y = fmaf(w1.y, xv.y, acc[i].y);
            acc[i].z = fmaf(w1.z, xv.y, acc[i].z);
            acc[i].w = fmaf(w1.w, xv.y, acc[i].w);
            acc[i].x = fmaf(w2.x, xv.z, acc[i].x);
            acc[i].y = fmaf(w2.y, xv.z, acc[i].y);
            acc[i].z = fmaf(w2.z, xv.z, acc[i].z);
            acc[i].w = fmaf(w2.w, xv.z, acc[i].w);
            acc[i].x = fmaf(w3.x, xv.w, acc[i].x);
            acc[i].y = fmaf(w3.y, xv.w, acc[i].y);
            acc[i].z = fmaf(w3.z, xv.w, acc[i].z);
            acc[i].w = fmaf(w3.w, xv.w, acc[i].w);
        }
    }
#pragma unroll
    for (int i = 0; i < 16; ++i)
        ((float4*)(xw + ((size_t)dir * S_LEN + t0 + i) * 1024))[tid] = acc[i];
}

// ---------------- LSTM recurrence ----------------
// 32 blocks x 256 threads. blk -> (dir = blk>>4, b = blk&15). Block owns
// h-dims [16b,16b+16) => 64 rows (4 gates x 16 dims). Weights live in LDS
// (64 KB/block, slot-permuted so every ds_read_b128 has consecutive lanes on
// consecutive float4s = conflict-free). NO register-resident weights: rounds
// 1-4 all lost to the allocator (remat/spill/scratch); LDS is deterministic.
// Thread (g=tid>>6, v=(lane>>2), u=lane&3) computes rows g*256+b*16+4u+j
// (j=0..3) over cols [16v,16v+16). Partials go to zp2[row][v] (padded 20) so
// the combiner reads them as 4x b128. Wave0 alone does activation (4 gates x
// 16 dims = 64 lanes), shfl-gather, c/h update, stamped {t+1,h} 8B publish to
// the IC ring, poll, hbf update. 2 barriers/step.
__global__ __launch_bounds__(256, 1) void lstm_rec(
    const float* __restrict__ whh_f, const float* __restrict__ whh_b,
    const float* __restrict__ xw, float* __restrict__ hs,
    unsigned long long* __restrict__ ring) {
    int blk = blockIdx.x;
    int dir = blk >> 4;
    int b = blk & 15;
    int tid = threadIdx.x;
    int g = tid >> 6;          // gate / wave
    int lane = tid & 63;
    int v = lane >> 2;         // col-chunk 0..15 (cols 16v..16v+15)
    int u = lane & 3;          // row subgroup (rows 4u..4u+3 within gate slice)

    __shared__ __align__(16) float wl[16384];   // 64 KB [slot 0..63][lane 0..63]x4
    __shared__ __align__(16) float hbf[320];    // dim d at (d>>4)*20 + (d&15)
    __shared__ __align__(16) float zp2[1280];   // [row 0..63]*20 + v
    float4* wl4 = (float4*)wl;

    const float* whh = dir ? whh_b : whh_f;
    // stage weights into the slot layout (once): slot = g*16 + j*4 + i holds
    // for each lane (v,u): Whh[g*256+b*16+4u+j][16v+4i .. +3]
#pragma unroll
    for (int j = 0; j < 4; ++j)
#pragma unroll
        for (int i = 0; i < 4; ++i)
            wl4[((g * 16 + j * 4 + i) << 6) + lane] =
                *(const float4*)(whh +
                    (size_t)(g * 256 + b * 16 + 4 * u + j) * 256 + 16 * v + 4 * i);

    const float* xwd = xw + (size_t)dir * S_LEN * 1024;
    float* hsd = hs + (size_t)dir * S_LEN * 256;
    unsigned long long* ringd = ring + dir * 512;   // [slot(2)][dim(256)]

    for (int i = tid; i < 320; i += 256) hbf[i] = 0.f;
    float c = 0.f;                              // wave0 lanes<16
    int crow = (lane >> 4) * 256 + b * 16 + (lane & 15);  // wave0 combine row
    float xw_cur = (g == 0) ? xwd[crow] : 0.f;
    __syncthreads();

    for (int t = 0; t < S_LEN; ++t) {
        // ---- matvec: h chunk (4x b128, 4-lane broadcast) + 16 weight b128 ----
        const float4* hb4 = (const float4*)hbf + v * 5;   // 20 floats = 5 float4
        float4 hc[4];
#pragma unroll
        for (int i = 0; i < 4; ++i) hc[i] = hb4[i];
        float4 acc[4];
#pragma unroll
        for (int j = 0; j < 4; ++j) acc[j] = make_float4(0.f, 0.f, 0.f, 0.f);
#pragma unroll
        for (int j = 0; j < 4; ++j) {
#pragma unroll
            for (int i = 0; i < 4; ++i) {
                float4 wv = wl4[((g * 16 + j * 4 + i) << 6) + lane];
                acc[j].x = fmaf(wv.x, hc[i].x, acc[j].x);
                acc[j].y = fmaf(wv.y, hc[i].y, acc[j].y);
                acc[j].z = fmaf(wv.z, hc[i].z, acc[j].z);
                acc[j].w = fmaf(wv.w, hc[i].w, acc[j].w);
            }
        }
#pragma unroll
        for (int j = 0; j < 4; ++j)
            zp2[(g * 16 + 4 * u + j) * 20 + v] =
                (acc[j].x + acc[j].y) + (acc[j].z + acc[j].w);
        __syncthreads();   // (A) zp2 ready

        if (g == 0) {
            // lane = g2*16 + s -> combine row (gate g2, dim s): 4x b128
            const float4* zrow = (const float4*)&zp2[lane * 20];
            float4 z0 = zrow[0], z1 = zrow[1], z2 = zrow[2], z3 = zrow[3];
            float z = xw_cur +
                (((z0.x + z0.y) + (z0.z + z0.w)) + ((z1.x + z1.y) + (z1.z + z1.w))) +
                (((z2.x + z2.y) + (z2.z + z2.w)) + ((z3.x + z3.y) + (z3.z + z3.w)));
            int g2 = lane >> 4;
            int tn = (t + 1 < S_LEN) ? t + 1 : t;
            float xw_next = xwd[(size_t)tn * 1024 + crow];  // prefetch under poll
            float act = (g2 == 2) ? tanhf(z) : 1.f / (1.f + expf(-z));
            float fg = __shfl(act, (lane & 15) + 16, 64);
            float gg = __shfl(act, (lane & 15) + 32, 64);
            float og = __shfl(act, (lane & 15) + 48, 64);
            unsigned long long* slot = ringd + (size_t)(t & 1) * 256;
            unsigned int want = (unsigned int)(t + 1);
            if (lane < 16) {
                c = fmaf(fg, c, act * gg);     // act == ig in lanes<16
                float h = og * tanhf(c);
                hsd[(size_t)t * 256 + b * 16 + lane] = h;
                unsigned long long pk = ((unsigned long long)want << 32) |
                                        (unsigned long long)__float_as_uint(h);
                __hip_atomic_store(&slot[b * 16 + lane], pk,
                                   __ATOMIC_RELAXED, __HIP_MEMORY_SCOPE_AGENT);
            }
            unsigned long long v0, v1, v2, v3;
            for (;;) {
                v0 = __hip_atomic_load(&slot[lane], __ATOMIC_RELAXED, __HIP_MEMORY_SCOPE_AGENT);
                v1 = __hip_atomic_load(&slot[lane + 64], __ATOMIC_RELAXED, __HIP_MEMORY_SCOPE_AGENT);
                v2 = __hip_atomic_load(&slot[lane + 128], __ATOMIC_RELAXED, __HIP_MEMORY_SCOPE_AGENT);
                v3 = __hip_atomic_load(&slot[lane + 192], __ATOMIC_RELAXED, __HIP_MEMORY_SCOPE_AGENT);
                bool ok = ((unsigned int)(v0 >> 32) == want) &
                          ((unsigned int)(v1 >> 32) == want) &
                          ((unsigned int)(v2 >> 32) == want) &
                          ((unsigned int)(v3 >> 32) == want);
                if (__all(ok)) break;
            }
            int sl = lane & 15, ch = lane >> 4;
            hbf[(ch + 0) * 20 + sl]  = __uint_as_float((unsigned int)v0);
            hbf[(ch + 4) * 20 + sl]  = __uint_as_float((unsigned int)v1);
            hbf[(ch + 8) * 20 + sl]  = __uint_as_float((unsigned int)v2);
            hbf[(ch + 12) * 20 + sl] = __uint_as_float((unsigned int)v3);
            xw_cur = xw_next;
        }
        __syncthreads();   // (C) hbf = h_t for everyone
    }
}

// ---------------- feats = [h_f, h_b] @ W_out^T + b_out ----------------
__global__ __launch_bounds__(64) void feats_k(const float* __restrict__ hs,
                                              const float* __restrict__ wout,
                                              const float* __restrict__ bout,
                                              float* __restrict__ feats) {
    int t = blockIdx.x, tau = blockIdx.y, lane = threadIdx.x;
    const float* hf = hs + (size_t)t * 256;
    const float* hbk = hs + (size_t)S_LEN * 256 + (size_t)(S_LEN - 1 - t) * 256;
    const float* w = wout + (size_t)tau * 512;
    float s = 0.f;
#pragma unroll
    for (int m = 0; m < 4; ++m) s = fmaf(w[lane + 64 * m], hf[lane + 64 * m], s);
#pragma unroll
    for (int m = 0; m < 4; ++m) s = fmaf(w[256 + lane + 64 * m], hbk[lane + 64 * m], s);
#pragma unroll
    for (int off = 32; off > 0; off >>= 1) s += __shfl_down(s, off, 64);
    if (lane == 0) feats[(size_t)t * NTAG + tau] = s + bout[tau];
}

// ---------------- Viterbi (single wave; bp table + path in LDS) ----------------
__global__ __launch_bounds__(64) void viterbi_k(const float* __restrict__ feats,
                                                const float* __restrict__ trans,
                                                float* __restrict__ out) {
    __shared__ float fstage[128 * NTAG];
    __shared__ unsigned char bp[S_LEN * NTAG];
    __shared__ float path[S_LEN];
    __shared__ float fvbuf[NTAG];
    __shared__ float term[NTAG];
    int tid = threadIdx.x;
    float tr[NTAG];
    float trstop = 0.f;
    if (tid < NTAG) {
#pragma unroll
        for (int j = 0; j < NTAG; ++j) tr[j] = trans[tid * NTAG + j];
        trstop = trans[STOP_TAG * NTAG + tid];
    }
    float fv = (tid == START_TAG) ? 0.f : NEGV;
    for (int t0 = 0; t0 < S_LEN; t0 += 128) {
        __syncthreads();
        for (int i = tid; i < 128 * NTAG; i += 64) fstage[i] = feats[(size_t)t0 * NTAG + i];
        __syncthreads();
        for (int tt = 0; tt < 128; ++tt) {
            int t = t0 + tt;
            if (tid < NTAG) fvbuf[tid] = fv;
            __syncthreads();
            if (tid < NTAG) {
                float best = -3.4e38f; int bj = 0;
#pragma unroll
                for (int j = 0; j < NTAG; ++j) {
                    float v = fvbuf[j] + tr[j];
                    if (v > best) { best = v; bj = j; }
                }
                bp[t * NTAG + tid] = (unsigned char)bj;
                fv = best + fstage[tt * NTAG + tid];
            }
            __syncthreads();
        }
    }
    if (tid < NTAG) term[tid] = fv + trstop;
    __syncthreads();
    if (tid == 0) {
        float best = -3.4e38f; int bi = 0;
#pragma unroll
        for (int i = 0; i < NTAG; ++i) {
            float v = term[i];
            if (v > best) { best = v; bi = i; }
        }
        out[0] = best;
        int tag = bi;
        for (int t = S_LEN - 1; t >= 0; --t) {
            path[t] = (float)tag;
            tag = bp[t * NTAG + tag];
        }
    }
    __syncthreads();
    for (int i = tid; i < S_LEN; i += 64) out[1 + i] = path[i];
}

extern "C" void kernel_launch(void* const* d_in, const int* in_sizes, int n_in,
                              void* d_out, int out_size, void* d_ws, size_t ws_size,
                              hipStream_t stream) {
    const int* sent = (const int*)d_in[0];
    const float* emb = (const float*)d_in[1];
    const float* wih_f = (const float*)d_in[2];
    const float* whh_f = (const float*)d_in[3];
    const float* bih_f = (const float*)d_in[4];
    const float* bhh_f = (const float*)d_in[5];
    const float* wih_b = (const float*)d_in[6];
    const float* whh_b = (const float*)d_in[7];
    const float* bih_b = (const float*)d_in[8];
    const float* bhh_b = (const float*)d_in[9];
    const float* wout = (const float*)d_in[10];
    const float* bout = (const float*)d_in[11];
    const float* trans = (const float*)d_in[12];

    float* ws = (float*)d_ws;
    float* xw = ws + XW_OFF;
    float* hs = ws + HS_OFF;
    float* wT = ws + WT_OFF;
    float* fe = ws + FE_OFF;
    unsigned long long* ring = (unsigned long long*)(ws + RING_OFF);

    hipLaunchKernelGGL(transpose_wih, dim3(8, 32, 2), dim3(32, 32), 0, stream,
                       wih_f, wih_b, wT);
    hipLaunchKernelGGL(xw_gemm, dim3(S_LEN / 16, 2), dim3(256), 0, stream,
                       sent, emb, wT, bih_f, bhh_f, bih_b, bhh_b, xw);
    hipLaunchKernelGGL(lstm_rec, dim3(32), dim3(256), 0, stream,
                       whh_f, whh_b, xw, hs, ring);
    hipLaunchKernelGGL(feats_k, dim3(S_LEN, NTAG), dim3(64), 0, stream,
                       hs, wout, bout, fe);
    hipLaunchKernelGGL(viterbi_k, dim3(1), dim3(64), 0, stream,
                       fe, trans, (float*)d_out);
}

// Round 6
// 8145.367 us; speedup vs baseline: 1.0039x; 1.0039x over previous
//
#include <hip/hip_runtime.h>
#include <math.h>

#define S_LEN 4096
#define HDIRC 256
#define NTAG 10
#define START_TAG 8
#define STOP_TAG 9
#define NEGV -10000.0f

// -------- workspace layout (float units) --------
#define XW_OFF 0UL
#define XW_SZ  (2UL * S_LEN * 1024)          // xw[dir][t][1024]
#define HS_OFF (XW_OFF + XW_SZ)
#define HS_SZ  (2UL * S_LEN * 256)           // hs[dir][t][256] (dir1 indexed by backward step)
#define WT_OFF (HS_OFF + HS_SZ)
#define WT_SZ  (2UL * 256 * 1024)            // WihT[dir][k][r]
#define FE_OFF (WT_OFF + WT_SZ)
#define FE_SZ  ((size_t)S_LEN * NTAG)        // feats[t][tag]
#define RING_OFF (FE_OFF + FE_SZ)            // even float offset -> 8B aligned
#define RING_SZ (2UL * 2 * 256 * 2)          // u64 ring[dir][slot][dim], as floats

// ---------------- Wih transpose: [1024][256] -> [256][1024] ----------------
__global__ void transpose_wih(const float* __restrict__ wf,
                              const float* __restrict__ wb,
                              float* __restrict__ wT) {
    __shared__ float tile[32][33];
    const float* src = blockIdx.z ? wb : wf;
    float* dst = wT + (size_t)blockIdx.z * 256 * 1024;
    int x = blockIdx.x * 32 + threadIdx.x;   // k  (0..255)
    int y = blockIdx.y * 32 + threadIdx.y;   // r  (0..1023)
    tile[threadIdx.y][threadIdx.x] = src[y * 256 + x];
    __syncthreads();
    int ko = blockIdx.x * 32 + threadIdx.y;
    int ro = blockIdx.y * 32 + threadIdx.x;
    dst[(size_t)ko * 1024 + ro] = tile[threadIdx.x][threadIdx.y];
}

// ---------------- xW = emb[sent] @ Wih^T + (bih+bhh) ----------------
// grid (S/8, 2), block 256: 1024 blocks (was 256 -> better CU coverage).
__global__ __launch_bounds__(256) void xw_gemm(
    const int* __restrict__ sent, const float* __restrict__ emb,
    const float* __restrict__ wT,
    const float* __restrict__ bih_f, const float* __restrict__ bhh_f,
    const float* __restrict__ bih_b, const float* __restrict__ bhh_b,
    float* __restrict__ xw) {
    int dir = blockIdx.y;
    int t0 = blockIdx.x * 8;
    int tid = threadIdx.x;
    __shared__ __align__(16) float xs[8][256];
    for (int i = 0; i < 8; ++i) {
        int t = t0 + i;
        int pos = dir ? (S_LEN - 1 - t) : t;
        int idx = sent[pos];
        xs[i][tid] = emb[(size_t)idx * 256 + tid];
    }
    __syncthreads();
    const float* w = wT + (size_t)dir * 256 * 1024;
    const float* bi = dir ? bih_b : bih_f;
    const float* bh = dir ? bhh_b : bhh_f;
    float4 bv;
    bv.x = bi[4 * tid + 0] + bh[4 * tid + 0];
    bv.y = bi[4 * tid + 1] + bh[4 * tid + 1];
    bv.z = bi[4 * tid + 2] + bh[4 * tid + 2];
    bv.w = bi[4 * tid + 3] + bh[4 * tid + 3];
    float4 acc[8];
#pragma unroll
    for (int i = 0; i < 8; ++i) acc[i] = bv;
    for (int k4 = 0; k4 < 64; ++k4) {
        float4 w0 = ((const float4*)(w + (size_t)(4 * k4 + 0) * 1024))[tid];
        float4 w1 = ((const float4*)(w + (size_t)(4 * k4 + 1) * 1024))[tid];
        float4 w2 = ((const float4*)(w + (size_t)(4 * k4 + 2) * 1024))[tid];
        float4 w3 = ((const float4*)(w + (size_t)(4 * k4 + 3) * 1024))[tid];
#pragma unroll
        for (int i = 0; i < 8; ++i) {
            float4 xv = *(const float4*)&xs[i][4 * k4];
            acc[i].x = fmaf(w0.x, xv.x, acc[i].x);
            acc[i].y = fmaf(w0.y, xv.x, acc[i].y);
            acc[i].z = fmaf(w0.z, xv.x, acc[i].z);
            acc[i].w = fmaf(w0.w, xv.x, acc[i].w);
            acc[i].x = fmaf(w1.x, xv.y, acc[i].x);
            acc[i].y = fmaf(w1.y, xv.y, acc[i].y);
            acc[i].z = fmaf(w1.z, xv.y, acc[i].z);
            acc[i].w = fmaf(w1.w, xv.y, acc[i].w);
            acc[i].x = fmaf(w2.x, xv.z, acc[i].x);
            acc[i].y = fmaf(w2.y, xv.z, acc[i].y);
            acc[i].z = fmaf(w2.z, xv.z, acc[i].z);
            acc[i].w = fmaf(w2.w, xv.z, acc[i].w);
            acc[i].x = fmaf(w3.x, xv.w, acc[i].x);
            acc[i].y = fmaf(w3.y, xv.w, acc[i].y);
            acc[i].z = fmaf(w3.z, xv.w, acc[i].z);
            acc[i].w = fmaf(w3.w, xv.w, acc[i].w);
        }
    }
#pragma unroll
    for (int i = 0; i < 8; ++i)
        ((float4*)(xw + ((size_t)dir * S_LEN + t0 + i) * 1024))[tid] = acc[i];
}

// ---------------- LSTM recurrence ----------------
// 32 blocks x 256 threads. blk -> (dir = blk>>4, b = blk&15). Block owns
// h-dims [16b,16b+16) => 64 rows (4 gates x 16 dims). Weights staged to LDS
// once (slot layout, conflict-free), then loaded to plain float4 locals
// before the t-loop: best case = register-resident matvec; worst case =
// compiler re-reads LDS (R5 perf). NO asm pins (R4's asm caused spill-panic).
// Per step: 64 static FMAs -> in-wave shfl_xor butterfly (rows never leave
// their wave; no zp2 LDS roundtrip) -> per-wave activation (16 lanes) ->
// actb -> barrier -> wave0: c/h, stamped {t+1,h} 8B publish to IC ring, poll
// 256 dims, hbf update -> barrier. 2 barriers/step.
__global__ __launch_bounds__(256, 1) void lstm_rec(
    const float* __restrict__ whh_f, const float* __restrict__ whh_b,
    const float* __restrict__ xw, float* __restrict__ hs,
    unsigned long long* __restrict__ ring) {
    int blk = blockIdx.x;
    int dir = blk >> 4;
    int b = blk & 15;
    int tid = threadIdx.x;
    int g = tid >> 6;          // gate / wave
    int lane = tid & 63;
    int v = lane >> 2;         // col-chunk 0..15 (cols 16v..16v+15)
    int u = lane & 3;          // row subgroup (rows 4u..4u+3 within gate slice)

    __shared__ __align__(16) float wl[16384];   // 64 KB staged weights
    __shared__ __align__(16) float hbf[320];    // dim d at (d>>4)*20 + (d&15)
    __shared__ __align__(16) float actb[64];    // [dim s][gate g] = actb[s*4+g]
    float4* wl4 = (float4*)wl;

    const float* whh = dir ? whh_b : whh_f;
    // stage: slot = g*16 + j*4 + i holds, per lane (v,u):
    //   Whh[g*256+b*16+4u+j][16v+4i .. +3]
#pragma unroll
    for (int j = 0; j < 4; ++j)
#pragma unroll
        for (int i = 0; i < 4; ++i)
            wl4[((g * 16 + j * 4 + i) << 6) + lane] =
                *(const float4*)(whh +
                    (size_t)(g * 256 + b * 16 + 4 * u + j) * 256 + 16 * v + 4 * i);

    const float* xwd = xw + (size_t)dir * S_LEN * 1024;
    float* hsd = hs + (size_t)dir * S_LEN * 256;
    unsigned long long* ringd = ring + dir * 512;   // [slot(2)][dim(256)]

    for (int i = tid; i < 320; i += 256) hbf[i] = 0.f;
    __syncthreads();

    // hoist weights into locals (static use only). Fallback if not kept
    // resident: in-loop ds_read == R5 behavior.
    float4 w00 = wl4[((g * 16 + 0) << 6) + lane];
    float4 w01 = wl4[((g * 16 + 1) << 6) + lane];
    float4 w02 = wl4[((g * 16 + 2) << 6) + lane];
    float4 w03 = wl4[((g * 16 + 3) << 6) + lane];
    float4 w10 = wl4[((g * 16 + 4) << 6) + lane];
    float4 w11 = wl4[((g * 16 + 5) << 6) + lane];
    float4 w12 = wl4[((g * 16 + 6) << 6) + lane];
    float4 w13 = wl4[((g * 16 + 7) << 6) + lane];
    float4 w20 = wl4[((g * 16 + 8) << 6) + lane];
    float4 w21 = wl4[((g * 16 + 9) << 6) + lane];
    float4 w22 = wl4[((g * 16 + 10) << 6) + lane];
    float4 w23 = wl4[((g * 16 + 11) << 6) + lane];
    float4 w30 = wl4[((g * 16 + 12) << 6) + lane];
    float4 w31 = wl4[((g * 16 + 13) << 6) + lane];
    float4 w32 = wl4[((g * 16 + 14) << 6) + lane];
    float4 w33 = wl4[((g * 16 + 15) << 6) + lane];

    float c = 0.f;                              // cell state (wave0 lanes<16)
    int crow = g * 256 + b * 16 + (lane & 15);  // this wave's combine row
    float xw_cur = (lane < 16) ? xwd[crow] : 0.f;
    int sel = lane & 3;                         // row-select for lanes<16

    for (int t = 0; t < S_LEN; ++t) {
        // ---- matvec: rows 4u+j over cols [16v,16v+16) ----
        const float4* hb4 = (const float4*)hbf + v * 5;   // 20 floats padded
        float4 h0 = hb4[0], h1 = hb4[1], h2 = hb4[2], h3 = hb4[3];
        float4 a0, a1, a2, a3;
        a0.x = w00.x * h0.x; a0.y = w00.y * h0.y; a0.z = w00.z * h0.z; a0.w = w00.w * h0.w;
        a1.x = w10.x * h0.x; a1.y = w10.y * h0.y; a1.z = w10.z * h0.z; a1.w = w10.w * h0.w;
        a2.x = w20.x * h0.x; a2.y = w20.y * h0.y; a2.z = w20.z * h0.z; a2.w = w20.w * h0.w;
        a3.x = w30.x * h0.x; a3.y = w30.y * h0.y; a3.z = w30.z * h0.z; a3.w = w30.w * h0.w;

        a0.x = fmaf(w01.x, h1.x, a0.x); a0.y = fmaf(w01.y, h1.y, a0.y);
        a0.z = fmaf(w01.z, h1.z, a0.z); a0.w = fmaf(w01.w, h1.w, a0.w);
        a1.x = fmaf(w11.x, h1.x, a1.x); a1.y = fmaf(w11.y, h1.y, a1.y);
        a1.z = fmaf(w11.z, h1.z, a1.z); a1.w = fmaf(w11.w, h1.w, a1.w);
        a2.x = fmaf(w21.x, h1.x, a2.x); a2.y = fmaf(w21.y, h1.y, a2.y);
        a2.z = fmaf(w21.z, h1.z, a2.z); a2.w = fmaf(w21.w, h1.w, a2.w);
        a3.x = fmaf(w31.x, h1.x, a3.x); a3.y = fmaf(w31.y, h1.y, a3.y);
        a3.z = fmaf(w31.z, h1.z, a3.z); a3.w = fmaf(w31.w, h1.w, a3.w);

        a0.x = fmaf(w02.x, h2.x, a0.x); a0.y = fmaf(w02.y, h2.y, a0.y);
        a0.z = fmaf(w02.z, h2.z, a0.z); a0.w = fmaf(w02.w, h2.w, a0.w);
        a1.x = fmaf(w12.x, h2.x, a1.x); a1.y = fmaf(w12.y, h2.y, a1.y);
        a1.z = fmaf(w12.z, h2.z, a1.z); a1.w = fmaf(w12.w, h2.w, a1.w);
        a2.x = fmaf(w22.x, h2.x, a2.x); a2.y = fmaf(w22.y, h2.y, a2.y);
        a2.z = fmaf(w22.z, h2.z, a2.z); a2.w = fmaf(w22.w, h2.w, a2.w);
        a3.x = fmaf(w32.x, h2.x, a3.x); a3.y = fmaf(w32.y, h2.y, a3.y);
        a3.z = fmaf(w32.z, h2.z, a3.z); a3.w = fmaf(w32.w, h2.w, a3.w);

        a0.x = fmaf(w03.x, h3.x, a0.x); a0.y = fmaf(w03.y, h3.y, a0.y);
        a0.z = fmaf(w03.z, h3.z, a0.z); a0.w = fmaf(w03.w, h3.w, a0.w);
        a1.x = fmaf(w13.x, h3.x, a1.x); a1.y = fmaf(w13.y, h3.y, a1.y);
        a1.z = fmaf(w13.z, h3.z, a1.z); a1.w = fmaf(w13.w, h3.w, a1.w);
        a2.x = fmaf(w23.x, h3.x, a2.x); a2.y = fmaf(w23.y, h3.y, a2.y);
        a2.z = fmaf(w23.z, h3.z, a2.z); a2.w = fmaf(w23.w, h3.w, a2.w);
        a3.x = fmaf(w33.x, h3.x, a3.x); a3.y = fmaf(w33.y, h3.y, a3.y);
        a3.z = fmaf(w33.z, h3.z, a3.z); a3.w = fmaf(w33.w, h3.w, a3.w);

        float s0 = (a0.x + a0.y) + (a0.z + a0.w);
        float s1 = (a1.x + a1.y) + (a1.z + a1.w);
        float s2 = (a2.x + a2.y) + (a2.z + a2.w);
        float s3 = (a3.x + a3.y) + (a3.z + a3.w);

        // ---- in-wave butterfly over the 16 v-lanes (same u) ----
#pragma unroll
        for (int off = 4; off < 64; off <<= 1) {
            s0 += __shfl_xor(s0, off, 64);
            s1 += __shfl_xor(s1, off, 64);
            s2 += __shfl_xor(s2, off, 64);
            s3 += __shfl_xor(s3, off, 64);
        }
        // lane L<16 takes row L: source lane L>>2 (u = L>>2), pick j = L&3
        int srcl = lane >> 2;
        float t0v = __shfl(s0, srcl, 64);
        float t1v = __shfl(s1, srcl, 64);
        float t2v = __shfl(s2, srcl, 64);
        float t3v = __shfl(s3, srcl, 64);
        float ss = (sel == 0) ? t0v : (sel == 1) ? t1v : (sel == 2) ? t2v : t3v;

        int tn = (t + 1 < S_LEN) ? t + 1 : t;
        float xw_next = 0.f;
        if (lane < 16) {
            float z = xw_cur + ss;
            float act = (g == 2) ? tanhf(z) : 1.f / (1.f + expf(-z));
            actb[(lane & 15) * 4 + g] = act;
            xw_next = xwd[(size_t)tn * 1024 + crow];   // prefetch under poll
        }
        __syncthreads();   // (A) actb ready

        if (g == 0) {
            unsigned long long* slot = ringd + (size_t)(t & 1) * 256;
            unsigned int want = (unsigned int)(t + 1);
            if (lane < 16) {
                float4 A = *(const float4*)&actb[lane * 4];  // i,f,g,o
                c = fmaf(A.y, c, A.x * A.z);
                float h = A.w * tanhf(c);
                hsd[(size_t)t * 256 + b * 16 + lane] = h;
                unsigned long long pk = ((unsigned long long)want << 32) |
                                        (unsigned long long)__float_as_uint(h);
                __hip_atomic_store(&slot[b * 16 + lane], pk,
                                   __ATOMIC_RELAXED, __HIP_MEMORY_SCOPE_AGENT);
            }
            unsigned long long v0, v1, v2, v3;
            for (;;) {
                v0 = __hip_atomic_load(&slot[lane], __ATOMIC_RELAXED, __HIP_MEMORY_SCOPE_AGENT);
                v1 = __hip_atomic_load(&slot[lane + 64], __ATOMIC_RELAXED, __HIP_MEMORY_SCOPE_AGENT);
                v2 = __hip_atomic_load(&slot[lane + 128], __ATOMIC_RELAXED, __HIP_MEMORY_SCOPE_AGENT);
                v3 = __hip_atomic_load(&slot[lane + 192], __ATOMIC_RELAXED, __HIP_MEMORY_SCOPE_AGENT);
                bool ok = ((unsigned int)(v0 >> 32) == want) &
                          ((unsigned int)(v1 >> 32) == want) &
                          ((unsigned int)(v2 >> 32) == want) &
                          ((unsigned int)(v3 >> 32) == want);
                if (__all(ok)) break;
            }
            int sl = lane & 15, ch = lane >> 4;
            hbf[(ch + 0) * 20 + sl]  = __uint_as_float((unsigned int)v0);
            hbf[(ch + 4) * 20 + sl]  = __uint_as_float((unsigned int)v1);
            hbf[(ch + 8) * 20 + sl]  = __uint_as_float((unsigned int)v2);
            hbf[(ch + 12) * 20 + sl] = __uint_as_float((unsigned int)v3);
        }
        xw_cur = xw_next;
        __syncthreads();   // (C) hbf = h_t for everyone
    }
}

// ---------------- feats = [h_f, h_b] @ W_out^T + b_out ----------------
__global__ __launch_bounds__(64) void feats_k(const float* __restrict__ hs,
                                              const float* __restrict__ wout,
                                              const float* __restrict__ bout,
                                              float* __restrict__ feats) {
    int t = blockIdx.x, tau = blockIdx.y, lane = threadIdx.x;
    const float* hf = hs + (size_t)t * 256;
    const float* hbk = hs + (size_t)S_LEN * 256 + (size_t)(S_LEN - 1 - t) * 256;
    const float* w = wout + (size_t)tau * 512;
    float s = 0.f;
#pragma unroll
    for (int m = 0; m < 4; ++m) s = fmaf(w[lane + 64 * m], hf[lane + 64 * m], s);
#pragma unroll
    for (int m = 0; m < 4; ++m) s = fmaf(w[256 + lane + 64 * m], hbk[lane + 64 * m], s);
#pragma unroll
    for (int off = 32; off > 0; off >>= 1) s += __shfl_down(s, off, 64);
    if (lane == 0) feats[(size_t)t * NTAG + tau] = s + bout[tau];
}

// ---------------- Viterbi: single wave, shfl-broadcast, no per-step barrier --
__global__ __launch_bounds__(64) void viterbi_k(const float* __restrict__ feats,
                                                const float* __restrict__ trans,
                                                float* __restrict__ out) {
    __shared__ float fstage[128 * NTAG];
    __shared__ unsigned char bp[S_LEN * NTAG];
    __shared__ float path[S_LEN];
    __shared__ float term[16];
    int tid = threadIdx.x;      // one wave; lane tau<10 owns fv[tau]
    int rr = (tid < NTAG) ? tid : 0;
    float tr[NTAG];
#pragma unroll
    for (int j = 0; j < NTAG; ++j) tr[j] = trans[rr * NTAG + j];
    float trstop = trans[STOP_TAG * NTAG + rr];
    float fv = (tid == START_TAG) ? 0.f : NEGV;

    for (int t0 = 0; t0 < S_LEN; t0 += 128) {
        __syncthreads();
        for (int i = tid; i < 128 * NTAG; i += 64) fstage[i] = feats[(size_t)t0 * NTAG + i];
        __syncthreads();
        for (int tt = 0; tt < 128; ++tt) {
            float b0 = __shfl(fv, 0, 64), b1 = __shfl(fv, 1, 64);
            float b2 = __shfl(fv, 2, 64), b3 = __shfl(fv, 3, 64);
            float b4 = __shfl(fv, 4, 64), b5 = __shfl(fv, 5, 64);
            float b6 = __shfl(fv, 6, 64), b7 = __shfl(fv, 7, 64);
            float b8 = __shfl(fv, 8, 64), b9 = __shfl(fv, 9, 64);
            float best = b0 + tr[0]; int bj = 0;
            float vv;
            vv = b1 + tr[1]; if (vv > best) { best = vv; bj = 1; }
            vv = b2 + tr[2]; if (vv > best) { best = vv; bj = 2; }
            vv = b3 + tr[3]; if (vv > best) { best = vv; bj = 3; }
            vv = b4 + tr[4]; if (vv > best) { best = vv; bj = 4; }
            vv = b5 + tr[5]; if (vv > best) { best = vv; bj = 5; }
            vv = b6 + tr[6]; if (vv > best) { best = vv; bj = 6; }
            vv = b7 + tr[7]; if (vv > best) { best = vv; bj = 7; }
            vv = b8 + tr[8]; if (vv > best) { best = vv; bj = 8; }
            vv = b9 + tr[9]; if (vv > best) { best = vv; bj = 9; }
            if (tid < NTAG) {
                bp[(t0 + tt) * NTAG + tid] = (unsigned char)bj;
                fv = best + fstage[tt * NTAG + tid];
            }
        }
    }
    if (tid < NTAG) term[tid] = fv + trstop;
    __syncthreads();
    if (tid == 0) {
        float best = -3.4e38f; int bi = 0;
#pragma unroll
        for (int i = 0; i < NTAG; ++i) {
            float v = term[i];
            if (v > best) { best = v; bi = i; }
        }
        out[0] = best;
        int tag = bi;
        for (int t = S_LEN - 1; t >= 0; --t) {
            path[t] = (float)tag;
            tag = bp[t * NTAG + tag];
        }
    }
    __syncthreads();
    for (int i = tid; i < S_LEN; i += 64) out[1 + i] = path[i];
}

extern "C" void kernel_launch(void* const* d_in, const int* in_sizes, int n_in,
                              void* d_out, int out_size, void* d_ws, size_t ws_size,
                              hipStream_t stream) {
    const int* sent = (const int*)d_in[0];
    const float* emb = (const float*)d_in[1];
    const float* wih_f = (const float*)d_in[2];
    const float* whh_f = (const float*)d_in[3];
    const float* bih_f = (const float*)d_in[4];
    const float* bhh_f = (const float*)d_in[5];
    const float* wih_b = (const float*)d_in[6];
    const float* whh_b = (const float*)d_in[7];
    const float* bih_b = (const float*)d_in[8];
    const float* bhh_b = (const float*)d_in[9];
    const float* wout = (const float*)d_in[10];
    const float* bout = (const float*)d_in[11];
    const float* trans = (const float*)d_in[12];

    float* ws = (float*)d_ws;
    float* xw = ws + XW_OFF;
    float* hs = ws + HS_OFF;
    float* wT = ws + WT_OFF;
    float* fe = ws + FE_OFF;
    unsigned long long* ring = (unsigned long long*)(ws + RING_OFF);

    hipLaunchKernelGGL(transpose_wih, dim3(8, 32, 2), dim3(32, 32), 0, stream,
                       wih_f, wih_b, wT);
    hipLaunchKernelGGL(xw_gemm, dim3(S_LEN / 8, 2), dim3(256), 0, stream,
                       sent, emb, wT, bih_f, bhh_f, bih_b, bhh_b, xw);
    hipLaunchKernelGGL(lstm_rec, dim3(32), dim3(256), 0, stream,
                       whh_f, whh_b, xw, hs, ring);
    hipLaunchKernelGGL(feats_k, dim3(S_LEN, NTAG), dim3(64), 0, stream,
                       hs, wout, bout, fe);
    hipLaunchKernelGGL(viterbi_k, dim3(1), dim3(64), 0, stream,
                       fe, trans, (float*)d_out);
}